// Round 1
// baseline (256.454 us; speedup 1.0000x reference)
//
#include <hip/hip_runtime.h>

#define NROW 16384
#define DDIM 128

typedef _Float16 f16x8 __attribute__((ext_vector_type(8)));
typedef float f32x4 __attribute__((ext_vector_type(4)));

__device__ __forceinline__ unsigned short f2h(float x) {
  union { _Float16 f; unsigned short u; } cvt;
  cvt.f = (_Float16)x;  // v_cvt_f16_f32, RNE
  return cvt.u;
}

// Raw barrier without the compiler's vmcnt(0) drain: lets prefetch loads
// stay in flight across the barrier (m97 barrier-drain workaround).
__device__ __forceinline__ void block_sync() {
  asm volatile("s_waitcnt lgkmcnt(0)" ::: "memory");  // ds_writes done
  __builtin_amdgcn_s_barrier();
  asm volatile("" ::: "memory");                      // no hoisting of reads
}

// ---------------- prep: ht[d][i] = fp16(h[i][d]) ----------------
__global__ __launch_bounds__(256) void prep_ht(const float* __restrict__ h,
                                               unsigned short* __restrict__ ht) {
  __shared__ unsigned short tile[DDIM][65];  // 65: 2-way-free transpose
  const int t = threadIdx.x;
  const int i0 = blockIdx.x * 64;
#pragma unroll
  for (int rep = 0; rep < 8; ++rep) {
    int idx = rep * 256 + t;          // 0..2047 float4s of a 64x128 tile
    int r = idx >> 5, c4 = idx & 31;
    const float4 v = *(const float4*)(h + (size_t)(i0 + r) * DDIM + c4 * 4);
    int c = c4 * 4;
    tile[c + 0][r] = f2h(v.x);
    tile[c + 1][r] = f2h(v.y);
    tile[c + 2][r] = f2h(v.z);
    tile[c + 3][r] = f2h(v.w);
  }
  __syncthreads();
#pragma unroll
  for (int rep = 0; rep < 4; ++rep) {
    int idx = rep * 256 + t;          // 0..1023 groups of 8
    int d = idx >> 3, io = (idx & 7) * 8;
    uint4 o;
    o.x = (unsigned)tile[d][io + 0] | ((unsigned)tile[d][io + 1] << 16);
    o.y = (unsigned)tile[d][io + 2] | ((unsigned)tile[d][io + 3] << 16);
    o.z = (unsigned)tile[d][io + 4] | ((unsigned)tile[d][io + 5] << 16);
    o.w = (unsigned)tile[d][io + 6] | ((unsigned)tile[d][io + 7] << 16);
    *(uint4*)(ht + (size_t)d * NROW + i0 + io) = o;
  }
}

// ---------------- fused: out = rownorm(exp(adj)) @ h ----------------
// BM=32 rows/block, BK=64, 4 waves: wave(wr,wc) owns 16 rows x 64 cols.
// LDS: A[2][32 rows][8 units of 16B], BT[2][128 d][8 units], XOR-swizzled
// (unit_slot = unit_sem ^ (row&7)) via pre-swizzled global source so LDS
// writes are perfectly linear and reads are 2-way (free).
__global__ __launch_bounds__(256, 2) void fused(const float* __restrict__ adj,
                                                const unsigned short* __restrict__ ht,
                                                float* __restrict__ out) {
  __shared__ __align__(16) char smem[40960];  // A: 2*4KB @0, BT: 2*16KB @8192
  __shared__ float lds_rs[32];
  const int t = threadIdx.x;
  const size_t m0 = (size_t)blockIdx.x * 32;

  // --- staging indices (pre-swizzled source chunk) ---
  const int srow = t >> 3;                         // 0..31
  const int chk = (t & 7) ^ (srow & 7);            // semantic 8-elem chunk
  const float* ap = adj + (m0 + srow) * (size_t)NROW + chk * 8;
  const unsigned short* hp = ht + (size_t)srow * NROW + chk * 8;

  // --- mfma indices ---
  const int l = t & 63, w = t >> 6;
  const int wr = w >> 1, wc = w & 1;
  const int lr = l & 15, kg = l >> 4;              // kg: k-group 0..3
  const int arow = wr * 16 + lr;                   // 0..31
  const int aoff0 = arow * 128 + (((kg    ) ^ (arow & 7)) << 4);
  const int aoff1 = arow * 128 + (((kg + 4) ^ (arow & 7)) << 4);
  const int d0 = wc * 64 + lr;                     // d&7 == lr&7 for all cf
  const int boff0 = d0 * 128 + (((kg    ) ^ (lr & 7)) << 4);
  const int boff1 = d0 * 128 + (((kg + 4) ^ (lr & 7)) << 4);

  f32x4 acc[4];
#pragma unroll
  for (int cf = 0; cf < 4; ++cf) acc[cf] = (f32x4){0.f, 0.f, 0.f, 0.f};
  float rs = 0.f;

  // prefetch tile 0
  float4 pa0 = *(const float4*)(ap);
  float4 pa1 = *(const float4*)(ap + 4);
  uint4 pb0 = *(const uint4*)(hp);
  uint4 pb1 = *(const uint4*)(hp + 32 * NROW);
  uint4 pb2 = *(const uint4*)(hp + 64 * NROW);
  uint4 pb3 = *(const uint4*)(hp + 96 * NROW);

  for (int it = 0; it < NROW / 64; ++it) {
    const int cur = it & 1;
    float4 a0 = pa0, a1 = pa1;
    uint4 b0 = pb0, b1 = pb1, b2 = pb2, b3 = pb3;

    // exp + fp16 pack + rowsum
    float e0 = __expf(a0.x), e1 = __expf(a0.y), e2 = __expf(a0.z), e3 = __expf(a0.w);
    float e4 = __expf(a1.x), e5 = __expf(a1.y), e6 = __expf(a1.z), e7 = __expf(a1.w);
    rs += ((e0 + e1) + (e2 + e3)) + ((e4 + e5) + (e6 + e7));
    uint4 aw;
    aw.x = (unsigned)f2h(e0) | ((unsigned)f2h(e1) << 16);
    aw.y = (unsigned)f2h(e2) | ((unsigned)f2h(e3) << 16);
    aw.z = (unsigned)f2h(e4) | ((unsigned)f2h(e5) << 16);
    aw.w = (unsigned)f2h(e6) | ((unsigned)f2h(e7) << 16);

    // issue next tile's global loads (stay in flight across raw barrier)
    if (it + 1 < NROW / 64) {
      const float* a = ap + (it + 1) * 64;
      pa0 = *(const float4*)a;
      pa1 = *(const float4*)(a + 4);
      const unsigned short* hb = hp + (it + 1) * 64;
      pb0 = *(const uint4*)(hb);
      pb1 = *(const uint4*)(hb + 32 * NROW);
      pb2 = *(const uint4*)(hb + 64 * NROW);
      pb3 = *(const uint4*)(hb + 96 * NROW);
    }

    // linear (conflict-free) LDS writes
    *(uint4*)(smem + cur * 4096 + t * 16) = aw;
    uint4* bb = (uint4*)(smem + 8192 + cur * 16384);
    bb[t] = b0; bb[t + 256] = b1; bb[t + 512] = b2; bb[t + 768] = b3;

    block_sync();

    const char* aB = smem + cur * 4096;
    const char* bB = smem + 8192 + cur * 16384;
    f16x8 af0 = *(const f16x8*)(aB + aoff0);
    f16x8 af1 = *(const f16x8*)(aB + aoff1);
#pragma unroll
    for (int cf = 0; cf < 4; ++cf) {
      f16x8 bf0 = *(const f16x8*)(bB + boff0 + cf * 2048);
      acc[cf] = __builtin_amdgcn_mfma_f32_16x16x32_f16(af0, bf0, acc[cf], 0, 0, 0);
    }
#pragma unroll
    for (int cf = 0; cf < 4; ++cf) {
      f16x8 bf1 = *(const f16x8*)(bB + boff1 + cf * 2048);
      acc[cf] = __builtin_amdgcn_mfma_f32_16x16x32_f16(af1, bf1, acc[cf], 0, 0, 0);
    }
  }

  // rowsum: 8 consecutive lanes share a row
  rs += __shfl_xor(rs, 1);
  rs += __shfl_xor(rs, 2);
  rs += __shfl_xor(rs, 4);
  if ((t & 7) == 0) lds_rs[t >> 3] = rs;
  __syncthreads();

  // epilogue: D[(kg*4+r)][lr] per fragment; divide by rowsum
#pragma unroll
  for (int r = 0; r < 4; ++r) {
    const int row_l = wr * 16 + kg * 4 + r;
    const float inv = 1.0f / lds_rs[row_l];
    float* orow = out + (m0 + row_l) * (size_t)DDIM + wc * 64 + lr;
#pragma unroll
    for (int cf = 0; cf < 4; ++cf) {
      orow[cf * 16] = acc[cf][r] * inv;
    }
  }
}

extern "C" void kernel_launch(void* const* d_in, const int* in_sizes, int n_in,
                              void* d_out, int out_size, void* d_ws, size_t ws_size,
                              hipStream_t stream) {
  (void)in_sizes; (void)n_in; (void)out_size; (void)ws_size;
  const float* h   = (const float*)d_in[0];
  const float* adj = (const float*)d_in[1];
  float* out = (float*)d_out;
  unsigned short* ht = (unsigned short*)d_ws;  // 128*16384 fp16 = 4 MB

  prep_ht<<<dim3(NROW / 64), dim3(256), 0, stream>>>(h, ht);
  fused<<<dim3(NROW / 32), dim3(256), 0, stream>>>(adj, ht, out);
}